// Round 7
// baseline (406.038 us; speedup 1.0000x reference)
//
#include <hip/hip_runtime.h>
#include <hip/hip_bf16.h>
#include <cstddef>
#include <cstdint>

// Problem dims (fixed by setup_inputs)
#define NB   32
#define LSEQ 1024
#define HDIM 1280
#define PDIM 128

typedef unsigned short ushort_t;
typedef __bf16 bf16x8 __attribute__((ext_vector_type(8)));
typedef float  f32x4  __attribute__((ext_vector_type(4)));

// ws layout (bytes):
//   [0,128)     : accb (32 floats)
//   [128,136)   : sums[2]
//   [256,...)   : wT bf16 [128][1280]            (~320 KB)
//   [E_OFF,...) : e bf16 [32768][128]            (8.4 MB)
//   [HSB_OFF,.) : hsb bf16 [32768][1280]         (84 MB)
#define WT_OFF  256
#define E_OFF   (WT_OFF + HDIM * PDIM * 2)
#define HSB_OFF (((E_OFF + (size_t)NB * LSEQ * PDIM * 2) + 255) & ~(size_t)255)

__device__ __forceinline__ ushort_t bf16_rne(float x) {
  unsigned u = __float_as_uint(x);
  unsigned r = u + 0x7fffu + ((u >> 16) & 1u);
  return (ushort_t)(r >> 16);
}

// ---------------------------------------------------------------------------
// k0: wT[n][k] = bf16(w[k][n]); block 0 zeroes accb+sums.
// ---------------------------------------------------------------------------
__global__ __launch_bounds__(256) void k0_wt(const float* __restrict__ pw,
                                             ushort_t* __restrict__ wT,
                                             float* __restrict__ wsf) {
  if (blockIdx.x == 0 && threadIdx.x < 64) wsf[threadIdx.x] = 0.0f;
  const int idx = blockIdx.x * 256 + threadIdx.x;
  const int k = idx >> 7, n = idx & 127;
  wT[(size_t)n * HDIM + k] = bf16_rne(pw[(size_t)k * PDIM + n]);
}

// ---------------------------------------------------------------------------
// k1a: pure streaming convert hs fp32 -> hsb bf16. Copy-µbench-shaped:
// grid-stride, 2x float4 load + 1x uint4 store per iter. THE experiment:
// if this crawls (<2 TB/s) the env (restore writeback) caps k1, not code.
// ---------------------------------------------------------------------------
__global__ __launch_bounds__(256) void k1a_cvt(const float* __restrict__ hs,
                                               ushort_t* __restrict__ hsb) {
  const int n8  = (NB * LSEQ * HDIM) / 8;  // 5,242,880 groups of 8
  const int nth = gridDim.x * 256;
  int i = blockIdx.x * 256 + threadIdx.x;
#pragma unroll 2
  for (; i < n8; i += nth) {
    const float4 a = *(const float4*)(hs + (size_t)i * 8);
    const float4 b = *(const float4*)(hs + (size_t)i * 8 + 4);
    union { ushort_t u[8]; uint4 v; } pk;
    pk.u[0] = bf16_rne(a.x); pk.u[1] = bf16_rne(a.y);
    pk.u[2] = bf16_rne(a.z); pk.u[3] = bf16_rne(a.w);
    pk.u[4] = bf16_rne(b.x); pk.u[5] = bf16_rne(b.y);
    pk.u[6] = bf16_rne(b.z); pk.u[7] = bf16_rne(b.w);
    *(uint4*)(hsb + (size_t)i * 8) = pk.v;
  }
}

// ---------------------------------------------------------------------------
// k1b: e = normalize(hsb @ w + b), bf16 in AND out. MFMA 16x16x32, no LDS.
// A-frags load directly in MFMA layout (16 B/lane, natural bf16 rows);
// 2-deep A prefetch + 1-deep B prefetch. hsb is freshly written -> L3-hot.
// ---------------------------------------------------------------------------
__global__ __launch_bounds__(256, 2) void k1b_mfma(const ushort_t* __restrict__ hsb,
                                                   const ushort_t* __restrict__ wT,
                                                   const float* __restrict__ pb,
                                                   ushort_t* __restrict__ e) {
  const int l  = threadIdx.x & 63;
  const int w  = threadIdx.x >> 6;
  const int m0 = blockIdx.x * 64 + w * 16;
  const int lm = l & 15, lq = l >> 4;

  f32x4 acc[8];
#pragma unroll
  for (int t = 0; t < 8; ++t) acc[t] = (f32x4){0.f, 0.f, 0.f, 0.f};

  float bias[8];
#pragma unroll
  for (int t = 0; t < 8; ++t) bias[t] = pb[t * 16 + lm];

  const ushort_t* arow = hsb + (size_t)(m0 + lm) * HDIM + lq * 8;
  const ushort_t* brow = wT + (size_t)lm * HDIM + lq * 8;

  bf16x8 Ac = *(const bf16x8*)(arow);
  bf16x8 An = *(const bf16x8*)(arow + 32);
  bf16x8 Bc[8], Bn[8];
#pragma unroll
  for (int t = 0; t < 8; ++t)
    Bc[t] = *(const bf16x8*)(brow + (size_t)t * 16 * HDIM);

#pragma unroll 2
  for (int s = 0; s < 40; ++s) {
    bf16x8 An2;
    if (s < 38) An2 = *(const bf16x8*)(arow + (s + 2) * 32);
    if (s < 39) {
#pragma unroll
      for (int t = 0; t < 8; ++t)
        Bn[t] = *(const bf16x8*)(brow + (size_t)t * 16 * HDIM + (s + 1) * 32);
    }
#pragma unroll
    for (int t = 0; t < 8; ++t)
      acc[t] = __builtin_amdgcn_mfma_f32_16x16x32_bf16(Ac, Bc[t], acc[t], 0, 0, 0);
    Ac = An; An = An2;
#pragma unroll
    for (int t = 0; t < 8; ++t) Bc[t] = Bn[t];
  }

  float inv[4];
#pragma unroll
  for (int r = 0; r < 4; ++r) {
    float s2 = 0.f;
#pragma unroll
    for (int t = 0; t < 8; ++t) {
      acc[t][r] += bias[t];
      s2 = fmaf(acc[t][r], acc[t][r], s2);
    }
    s2 += __shfl_xor(s2, 1, 64);
    s2 += __shfl_xor(s2, 2, 64);
    s2 += __shfl_xor(s2, 4, 64);
    s2 += __shfl_xor(s2, 8, 64);
    inv[r] = 1.0f / sqrtf(s2);
  }

#pragma unroll
  for (int t = 0; t < 8; ++t)
#pragma unroll
    for (int r = 0; r < 4; ++r)
      e[(size_t)(m0 + lq * 4 + r) * PDIM + t * 16 + lm] =
          bf16_rne(acc[t][r] * inv[r]);
}

// ---------------------------------------------------------------------------
// k2: flash-style loss, 16 anchors/block (2048 blocks), depth-3 rotating
// software pipeline on the j-tiles (fully unrolled -> static registers).
// Stats accumulate in registers off the MFMA C-fragment (|sv|<=14.3,
// unshifted exp safe in fp32 — verified rounds 2-6).
// ---------------------------------------------------------------------------
__global__ __launch_bounds__(256, 4) void k2_loss(const ushort_t* __restrict__ e,
                                                  const int* __restrict__ mask,
                                                  const int* __restrict__ labels,
                                                  float* __restrict__ accb) {
  __shared__ float part[4][16][3];

  const int tid = threadIdx.x;
  const int l = tid & 63, w = tid >> 6;
  const int b  = blockIdx.x >> 6;
  const int i0 = (blockIdx.x & 63) << 4;
  const int lm = l & 15, lq = l >> 4;

  const ushort_t* eb   = e + (size_t)b * LSEQ * PDIM;
  const int*      mrow = mask + b * LSEQ;
  const int*      lrow = labels + b * LSEQ;

  bf16x8 af[4];
  {
    const ushort_t* aptr = eb + (size_t)(i0 + lm) * PDIM + lq * 8;
#pragma unroll
    for (int c = 0; c < 4; ++c) af[c] = *(const bf16x8*)(aptr + c * 32);
  }

  int  li[4], ar[4];
  bool vi[4];
#pragma unroll
  for (int r = 0; r < 4; ++r) {
    ar[r] = i0 + lq * 4 + r;
    li[r] = lrow[ar[r]];
    vi[r] = (mrow[ar[r]] != 0) && (li[r] != -100);
  }

  float d[4] = {}, ps[4] = {}, pc[4] = {};
  const float invT = 1.0f / 0.07f;
  const int jt0 = w * 16;

  bf16x8 Bb[3][4];
  int lj[3], mj[3];
  auto LOAD = [&](int slot, int jt) {
    const int j = jt * 16 + lm;
    const ushort_t* bptr = eb + (size_t)j * PDIM + lq * 8;
#pragma unroll
    for (int c = 0; c < 4; ++c) Bb[slot][c] = *(const bf16x8*)(bptr + c * 32);
    lj[slot] = lrow[j];
    mj[slot] = mrow[j];
  };
  LOAD(0, jt0); LOAD(1, jt0 + 1); LOAD(2, jt0 + 2);

#pragma unroll
  for (int s = 0; s < 16; ++s) {
    const int slot = s % 3;
    const int j = (jt0 + s) * 16 + lm;
    const bool cvj = (mj[slot] != 0) && (lj[slot] != -100);
    const int ljc = lj[slot];

    f32x4 acc = (f32x4){0.f, 0.f, 0.f, 0.f};
#pragma unroll
    for (int c = 0; c < 4; ++c)
      acc = __builtin_amdgcn_mfma_f32_16x16x32_bf16(af[c], Bb[slot][c], acc, 0, 0, 0);

    if (s + 3 < 16) LOAD(slot, jt0 + s + 3);

#pragma unroll
    for (int r = 0; r < 4; ++r) {
      const float sv = acc[r] * invT;
      const bool dm  = cvj && (j != ar[r]);
      const float ex = __expf(sv);
      d[r] += dm ? ex : 0.f;
      const bool pos = dm && (ljc == li[r]) && vi[r];
      ps[r] += pos ? sv : 0.f;
      pc[r] += pos ? 1.f : 0.f;
    }
  }

#pragma unroll
  for (int r = 0; r < 4; ++r) {
#pragma unroll
    for (int off = 1; off < 16; off <<= 1) {
      d[r]  += __shfl_xor(d[r], off, 64);
      ps[r] += __shfl_xor(ps[r], off, 64);
      pc[r] += __shfl_xor(pc[r], off, 64);
    }
  }
  if (lm == 0) {
#pragma unroll
    for (int r = 0; r < 4; ++r) {
      part[w][lq * 4 + r][0] = d[r];
      part[w][lq * 4 + r][1] = ps[r];
      part[w][lq * 4 + r][2] = pc[r];
    }
  }
  __syncthreads();

  if (tid < 16) {
    float D = 0.f, P = 0.f, C = 0.f;
#pragma unroll
    for (int w2 = 0; w2 < 4; ++w2) {
      D += part[w2][tid][0];
      P += part[w2][tid][1];
      C += part[w2][tid][2];
    }
    const float logD = logf(D + 1e-12f);
    float al = (P - C * logD) / (C + 1e-12f);
#pragma unroll
    for (int off = 1; off < 16; off <<= 1) al += __shfl_xor(al, off, 64);
    if (tid == 0) atomicAdd(&accb[b], al);
  }
}

// ---------------------------------------------------------------------------
// k2b: per-batch finalize (32 blocks) -> atomic loss/ok sums.
// ---------------------------------------------------------------------------
__global__ __launch_bounds__(256) void k2b_batch(const int* __restrict__ mask,
                                                 const int* __restrict__ labels,
                                                 const float* __restrict__ accb,
                                                 float* __restrict__ sums) {
  __shared__ int scm[4], scv[4];
  const int b = blockIdx.x;
  const int tid = threadIdx.x;
  const int l = tid & 63, w = tid >> 6;

  const int base = b * LSEQ + tid * 4;
  const int4 mv = *(const int4*)(mask + base);
  const int4 lv = *(const int4*)(labels + base);
  int cm = mv.x + mv.y + mv.z + mv.w;
  int cv = ((mv.x != 0 && lv.x != -100) ? 1 : 0) +
           ((mv.y != 0 && lv.y != -100) ? 1 : 0) +
           ((mv.z != 0 && lv.z != -100) ? 1 : 0) +
           ((mv.w != 0 && lv.w != -100) ? 1 : 0);
#pragma unroll
  for (int off = 1; off < 64; off <<= 1) {
    cm += __shfl_xor(cm, off, 64);
    cv += __shfl_xor(cv, off, 64);
  }
  if (l == 0) { scm[w] = cm; scv[w] = cv; }
  __syncthreads();
  if (tid == 0) {
    const int CM = scm[0] + scm[1] + scm[2] + scm[3];
    const int CV = scv[0] + scv[1] + scv[2] + scv[3];
    const bool ok = (CM >= 2);
    const float lossb = ok ? (-accb[b] / fmaxf((float)CV, 1.0f)) : 0.0f;
    atomicAdd(&sums[0], lossb);
    atomicAdd(&sums[1], ok ? 1.0f : 0.0f);
  }
}

// ---------------------------------------------------------------------------
// k3: final divide.
// ---------------------------------------------------------------------------
__global__ void k3_final(const float* __restrict__ sums,
                         float* __restrict__ out) {
  if (threadIdx.x == 0) out[0] = sums[0] / fmaxf(sums[1], 1.0f);
}

// ---------------------------------------------------------------------------
extern "C" void kernel_launch(void* const* d_in, const int* in_sizes, int n_in,
                              void* d_out, int out_size, void* d_ws, size_t ws_size,
                              hipStream_t stream) {
  (void)in_sizes; (void)n_in; (void)out_size; (void)ws_size;
  const float* hs     = (const float*)d_in[0];
  const float* pw     = (const float*)d_in[1];
  const float* pb     = (const float*)d_in[2];
  const int*   mask   = (const int*)d_in[3];
  const int*   labels = (const int*)d_in[4];
  float* out = (float*)d_out;

  char* wsb = (char*)d_ws;
  float*    wsf  = (float*)wsb;
  float*    accb = wsf;        // floats [0,32)
  float*    sums = wsf + 32;   // floats [32,34)
  ushort_t* wT   = (ushort_t*)(wsb + WT_OFF);
  ushort_t* e    = (ushort_t*)(wsb + E_OFF);
  ushort_t* hsb  = (ushort_t*)(wsb + HSB_OFF);

  k0_wt<<<(HDIM * PDIM) / 256, 256, 0, stream>>>(pw, wT, wsf);
  k1a_cvt<<<1024, 256, 0, stream>>>(hs, hsb);
  k1b_mfma<<<(NB * LSEQ) / 64, 256, 0, stream>>>(hsb, wT, pb, e);
  k2_loss<<<NB * 64, 256, 0, stream>>>(e, mask, labels, accb);
  k2b_batch<<<NB, 256, 0, stream>>>(mask, labels, accb, sums);
  k3_final<<<1, 64, 0, stream>>>(sums, out);
}